// Round 2
// baseline (422.736 us; speedup 1.0000x reference)
//
#include <hip/hip_runtime.h>
#include <stdint.h>

#define Bb 128
#define Pp 4096
#define Ff 32
#define Kk 8
#define Dd 64

constexpr float EPS_ATTN_ = 1e-8f;
constexpr float EPS_LN_   = 1e-5f;
constexpr float SCALE_    = 0.125f;  // 64^-0.5

typedef __attribute__((ext_vector_type(8))) short short8;
typedef __attribute__((ext_vector_type(4))) float floatx4;

__device__ __forceinline__ unsigned short f2bf(float f) {
  union { float f; unsigned u; } c; c.f = f;
  unsigned u = c.u + 0x7fffu + ((c.u >> 16) & 1u);  // RNE
  return (unsigned short)(u >> 16);
}
__device__ __forceinline__ float wsum(float v) {
  v += __shfl_xor(v, 1, 64);  v += __shfl_xor(v, 2, 64);
  v += __shfl_xor(v, 4, 64);  v += __shfl_xor(v, 8, 64);
  v += __shfl_xor(v, 16, 64); v += __shfl_xor(v, 32, 64);
  return v;
}

// ---------------- K0: slots0 = mu + |sigma|*noise ; q1 = LN(slots0)@Wq^T * SCALE ; zero acc1
__global__ __launch_bounds__(512) void init_kernel(
    const float* __restrict__ noise, const float* __restrict__ smu,
    const float* __restrict__ ssig, const float* __restrict__ Wq,
    const float* __restrict__ lsg, const float* __restrict__ lsb,
    float* __restrict__ slots, unsigned short* __restrict__ q_bf,
    float* __restrict__ accu, float* __restrict__ accs) {
  const int b = blockIdx.x;
  const int k = threadIdx.x >> 6;   // wave = slot
  const int j = threadIdx.x & 63;   // lane = d
  __shared__ float lnv[Kk][Dd];
  const size_t rk = (size_t)b * Kk + k;
  float s0 = smu[j] + fabsf(ssig[j]) * noise[rk * Dd + j];
  slots[rk * Dd + j] = s0;
  float mu  = wsum(s0) * (1.f / 64.f);
  float dc  = s0 - mu;
  float var = wsum(dc * dc) * (1.f / 64.f);
  float xn  = dc * rsqrtf(var + EPS_LN_) * lsg[j] + lsb[j];
  lnv[k][j] = xn;
  __syncthreads();
  float q = 0.f;
  #pragma unroll 8
  for (int d = 0; d < Dd; ++d) q = fmaf(Wq[j * Dd + d], lnv[k][d], q);
  q_bf[((size_t)b * 16 + k) * Dd + j]     = f2bf(q * SCALE_);
  q_bf[((size_t)b * 16 + k + 8) * Dd + j] = 0;   // zero-pad rows 8..15 (MFMA M=16)
  accu[rk * Dd + j] = 0.f;
  if (j == 0) accs[rk] = 0.f;
}

// ---------------- A: x -> LN -> k (pixel-major bf16), v (d-major/transposed bf16)
__global__ __launch_bounds__(256) void kv_kernel(
    const float* __restrict__ x, const float* __restrict__ Wk,
    const float* __restrict__ Wv, const float* __restrict__ lg,
    const float* __restrict__ lb, unsigned short* __restrict__ k_bf,
    unsigned short* __restrict__ vT_bf) {
  const int b  = blockIdx.x;
  const int px = blockIdx.y * 256 + threadIdx.x;
  const float* xr = x + ((size_t)b * Pp + px) * Ff;
  float xv[Ff];
  #pragma unroll
  for (int j = 0; j < Ff; j += 4) {
    float4 t = *(const float4*)(xr + j);
    xv[j] = t.x; xv[j+1] = t.y; xv[j+2] = t.z; xv[j+3] = t.w;
  }
  float mu = 0.f;
  #pragma unroll
  for (int j = 0; j < Ff; ++j) mu += xv[j];
  mu *= (1.f / Ff);
  float var = 0.f;
  #pragma unroll
  for (int j = 0; j < Ff; ++j) { float d = xv[j] - mu; var = fmaf(d, d, var); }
  var *= (1.f / Ff);
  float rr = rsqrtf(var + EPS_LN_);
  #pragma unroll
  for (int j = 0; j < Ff; ++j) xv[j] = (xv[j] - mu) * rr * lg[j] + lb[j];

  unsigned short* ko = k_bf + ((size_t)b * Pp + px) * Dd;
  #pragma unroll 1
  for (int d8 = 0; d8 < 8; ++d8) {
    short8 pk;
    #pragma unroll
    for (int dd = 0; dd < 8; ++dd) {
      const float* wr = Wk + (d8 * 8 + dd) * Ff;   // wave-uniform -> s_load
      float a = 0.f;
      #pragma unroll
      for (int j = 0; j < Ff; ++j) a = fmaf(wr[j], xv[j], a);
      pk[dd] = (short)f2bf(a);
    }
    *(short8*)(ko + d8 * 8) = pk;
  }
  unsigned short* vo = vT_bf + (size_t)b * Dd * Pp + px;   // [b][d][p]
  #pragma unroll 1
  for (int d8 = 0; d8 < 8; ++d8) {
    #pragma unroll
    for (int dd = 0; dd < 8; ++dd) {
      const float* wr = Wv + (d8 * 8 + dd) * Ff;
      float a = 0.f;
      #pragma unroll
      for (int j = 0; j < Ff; ++j) a = fmaf(wr[j], xv[j], a);
      vo[(size_t)(d8 * 8 + dd) * Pp] = f2bf(a);   // coalesced across lanes (px)
    }
  }
}

// ---------------- H: dots=q@k^T (MFMA) -> softmax over slots (+eps) -> acc += a@v (MFMA)
template <bool LAST>
__global__ __launch_bounds__(256) void attn_kernel(
    const unsigned short* __restrict__ q_bf,
    const unsigned short* __restrict__ k_bf,
    const unsigned short* __restrict__ vT_bf,
    float* __restrict__ accu, float* __restrict__ accs,
    float* __restrict__ attn_out) {
  const int b    = blockIdx.x;
  const int p0   = blockIdx.y * 256;
  const int w    = threadIdx.x >> 6;
  const int lane = threadIdx.x & 63;
  const int m    = lane & 15;
  const int quad = lane >> 4;
  __shared__ __align__(16) unsigned short A_lds[4][16][72];  // per-wave attn tile, +8 pad

  // A-frag for phase1: q[slot m][d = quad*8+j (+32)]
  const unsigned short* qp = q_bf + ((size_t)b * 16 + m) * Dd + quad * 8;
  const short8 aq0 = *(const short8*)(qp);
  const short8 aq1 = *(const short8*)(qp + 32);

  float Ss0 = 0.f, Ss1 = 0.f, Ss2 = 0.f, Ss3 = 0.f;
  floatx4 Cg0 = {0.f,0.f,0.f,0.f}, Cg1 = {0.f,0.f,0.f,0.f},
          Cg2 = {0.f,0.f,0.f,0.f}, Cg3 = {0.f,0.f,0.f,0.f};

  const int pw = p0 + w * 64;
  // ---- phase 1: dots + per-pixel softmax over K=8 slots
  #pragma unroll
  for (int t = 0; t < 4; ++t) {
    const int pt = pw + t * 16;
    // B-frag: k[pixel n=m][d = quad*8+j (+32)] straight from global (pixel-major)
    const unsigned short* kp = k_bf + ((size_t)b * Pp + pt + m) * Dd + quad * 8;
    short8 bk0 = *(const short8*)(kp);
    short8 bk1 = *(const short8*)(kp + 32);
    floatx4 C = {0.f, 0.f, 0.f, 0.f};
    C = __builtin_amdgcn_mfma_f32_16x16x32_bf16(aq0, bk0, C, 0, 0, 0);
    C = __builtin_amdgcn_mfma_f32_16x16x32_bf16(aq1, bk1, C, 0, 0, 0);
    // C: col=lane&15=pixel, row=quad*4+r=slot. 8 slot values live in lanes {l, l^16}.
    float mx = fmaxf(fmaxf(C[0], C[1]), fmaxf(C[2], C[3]));
    mx = fmaxf(mx, __shfl_xor(mx, 16, 64));
    float e0 = __expf(C[0] - mx), e1 = __expf(C[1] - mx),
          e2 = __expf(C[2] - mx), e3 = __expf(C[3] - mx);
    float s = e0 + e1 + e2 + e3;
    s += __shfl_xor(s, 16, 64);
    float inv = 1.f / s;
    float a0 = fmaf(e0, inv, EPS_ATTN_), a1 = fmaf(e1, inv, EPS_ATTN_);
    float a2 = fmaf(e2, inv, EPS_ATTN_), a3 = fmaf(e3, inv, EPS_ATTN_);
    Ss0 += a0; Ss1 += a1; Ss2 += a2; Ss3 += a3;
    unsigned short h0 = f2bf(a0), h1 = f2bf(a1), h2 = f2bf(a2), h3 = f2bf(a3);
    const int r0 = quad * 4;  // quads 2,3 write rows 8..15 (finite garbage, only feeds ignored C rows)
    A_lds[w][r0 + 0][t * 16 + m] = h0;
    A_lds[w][r0 + 1][t * 16 + m] = h1;
    A_lds[w][r0 + 2][t * 16 + m] = h2;
    A_lds[w][r0 + 3][t * 16 + m] = h3;
    if (LAST && quad < 2) {
      // f32 output (reference output dtype is float32!)
      float* ao = attn_out + ((size_t)b * Kk + r0) * Pp + pt + m;
      ao[0] = a0; ao[Pp] = a1; ao[2 * (size_t)Pp] = a2; ao[3 * (size_t)Pp] = a3;
    }
  }
  __syncthreads();
  // ---- phase 2: acc[slot][d] += a @ v  (A from LDS, B from transposed v in global)
  #pragma unroll
  for (int ks = 0; ks < 2; ++ks) {
    const short8 af = *(const short8*)(&A_lds[w][m][ks * 32 + quad * 8]);  // A[slot m][px]
    const unsigned short* vb = vT_bf + (size_t)b * Dd * Pp + pw + ks * 32 + quad * 8;
    short8 bv0 = *(const short8*)(vb + (size_t)(m)      * Pp);  // B[px][d = g*16+m]
    short8 bv1 = *(const short8*)(vb + (size_t)(16 + m) * Pp);
    short8 bv2 = *(const short8*)(vb + (size_t)(32 + m) * Pp);
    short8 bv3 = *(const short8*)(vb + (size_t)(48 + m) * Pp);
    Cg0 = __builtin_amdgcn_mfma_f32_16x16x32_bf16(af, bv0, Cg0, 0, 0, 0);
    Cg1 = __builtin_amdgcn_mfma_f32_16x16x32_bf16(af, bv1, Cg1, 0, 0, 0);
    Cg2 = __builtin_amdgcn_mfma_f32_16x16x32_bf16(af, bv2, Cg2, 0, 0, 0);
    Cg3 = __builtin_amdgcn_mfma_f32_16x16x32_bf16(af, bv3, Cg3, 0, 0, 0);
  }
  // ---- epilogue: reduce attn row-sums over the 16 pixels (lanes differing in m)
  Ss0 += __shfl_xor(Ss0,1,64); Ss0 += __shfl_xor(Ss0,2,64); Ss0 += __shfl_xor(Ss0,4,64); Ss0 += __shfl_xor(Ss0,8,64);
  Ss1 += __shfl_xor(Ss1,1,64); Ss1 += __shfl_xor(Ss1,2,64); Ss1 += __shfl_xor(Ss1,4,64); Ss1 += __shfl_xor(Ss1,8,64);
  Ss2 += __shfl_xor(Ss2,1,64); Ss2 += __shfl_xor(Ss2,2,64); Ss2 += __shfl_xor(Ss2,4,64); Ss2 += __shfl_xor(Ss2,8,64);
  Ss3 += __shfl_xor(Ss3,1,64); Ss3 += __shfl_xor(Ss3,2,64); Ss3 += __shfl_xor(Ss3,4,64); Ss3 += __shfl_xor(Ss3,8,64);
  if (quad < 2) {
    const int row = quad * 4;
    float* up = accu + ((size_t)b * Kk + row) * Dd + m;
    #pragma unroll
    for (int r = 0; r < 4; ++r) {
      atomicAdd(up + (size_t)r * Dd + 0,  Cg0[r]);
      atomicAdd(up + (size_t)r * Dd + 16, Cg1[r]);
      atomicAdd(up + (size_t)r * Dd + 32, Cg2[r]);
      atomicAdd(up + (size_t)r * Dd + 48, Cg3[r]);
    }
    if (m == 0) {
      atomicAdd(&accs[b * Kk + row + 0], Ss0);
      atomicAdd(&accs[b * Kk + row + 1], Ss1);
      atomicAdd(&accs[b * Kk + row + 2], Ss2);
      atomicAdd(&accs[b * Kk + row + 3], Ss3);
    }
  }
}

// ---------------- G: updates=U/S -> GRUCell -> +FF -> slots' ; next q (or final f32 out)
template <bool LAST>
__global__ __launch_bounds__(512) void gru_kernel(
    const float* __restrict__ accu, const float* __restrict__ accs,
    float* __restrict__ slots,
    const float* __restrict__ W_ih, const float* __restrict__ W_hh,
    const float* __restrict__ b_ih, const float* __restrict__ b_hh,
    const float* __restrict__ fg, const float* __restrict__ fb,
    const float* __restrict__ W1, const float* __restrict__ b1,
    const float* __restrict__ W2, const float* __restrict__ b2,
    const float* __restrict__ lsg, const float* __restrict__ lsb,
    const float* __restrict__ Wq,
    unsigned short* __restrict__ q_bf,
    float* __restrict__ accu2, float* __restrict__ accs2,
    float* __restrict__ out_slots) {
  const int b = blockIdx.x;
  const int k = threadIdx.x >> 6;   // wave = slot row
  const int j = threadIdx.x & 63;   // lane = dim / gate index (192 = 3*64 chunks!)
  __shared__ float Ub[Kk][Dd];
  __shared__ float Hb[Kk][Dd];
  __shared__ float Tb[Kk][2 * Dd];
  const size_t rk = (size_t)b * Kk + k;
  const float S = accs[rk];
  const float u = accu[rk * Dd + j] / S;   // normalize over pixels (scalar per b,k)
  const float h = slots[rk * Dd + j];
  Ub[k][j] = u;
  Hb[k][j] = h;
  __syncthreads();
  float gr = b_ih[j], gz = b_ih[64 + j], gn = b_ih[128 + j];
  float hr = b_hh[j], hz = b_hh[64 + j], hn_ = b_hh[128 + j];
  #pragma unroll 4
  for (int d = 0; d < Dd; ++d) {
    const float ud = Ub[k][d], hd = Hb[k][d];
    gr  = fmaf(W_ih[(size_t)j * Dd + d],          ud, gr);
    gz  = fmaf(W_ih[(size_t)(64 + j) * Dd + d],   ud, gz);
    gn  = fmaf(W_ih[(size_t)(128 + j) * Dd + d],  ud, gn);
    hr  = fmaf(W_hh[(size_t)j * Dd + d],          hd, hr);
    hz  = fmaf(W_hh[(size_t)(64 + j) * Dd + d],   hd, hz);
    hn_ = fmaf(W_hh[(size_t)(128 + j) * Dd + d],  hd, hn_);
  }
  const float r = 1.f / (1.f + __expf(-(gr + hr)));
  const float z = 1.f / (1.f + __expf(-(gz + hz)));
  const float n = tanhf(fmaf(r, hn_, gn));
  const float hnew = fmaf(z, h - n, n);    // (1-z)*n + z*h
  // ff layernorm
  float mu  = wsum(hnew) * (1.f / 64.f);
  float dc  = hnew - mu;
  float var = wsum(dc * dc) * (1.f / 64.f);
  float fi  = dc * rsqrtf(var + EPS_LN_) * fg[j] + fb[j];
  __syncthreads();
  Ub[k][j] = fi;
  __syncthreads();
  float f1a = b1[j], f1b = b1[64 + j];
  #pragma unroll 4
  for (int d = 0; d < Dd; ++d) {
    const float t = Ub[k][d];
    f1a = fmaf(W1[(size_t)j * Dd + d],        t, f1a);
    f1b = fmaf(W1[(size_t)(64 + j) * Dd + d], t, f1b);
  }
  f1a = fmaxf(f1a, 0.f);
  f1b = fmaxf(f1b, 0.f);
  Tb[k][j]      = f1a;
  Tb[k][64 + j] = f1b;
  __syncthreads();
  float o = b2[j];
  #pragma unroll 4
  for (int e = 0; e < 2 * Dd; ++e) o = fmaf(W2[(size_t)j * 2 * Dd + e], Tb[k][e], o);
  const float sn = hnew + o;
  if (!LAST) {
    slots[rk * Dd + j] = sn;   // safe: every thread re-writes only the element it read
    float mq = wsum(sn) * (1.f / 64.f);
    float dq = sn - mq;
    float vq = wsum(dq * dq) * (1.f / 64.f);
    float xq = dq * rsqrtf(vq + EPS_LN_) * lsg[j] + lsb[j];
    Ub[k][j] = xq;
    __syncthreads();
    float q = 0.f;
    #pragma unroll 8
    for (int d = 0; d < Dd; ++d) q = fmaf(Wq[(size_t)j * Dd + d], Ub[k][d], q);
    q_bf[((size_t)b * 16 + k) * Dd + j]     = f2bf(q * SCALE_);
    q_bf[((size_t)b * 16 + k + 8) * Dd + j] = 0;
    accu2[rk * Dd + j] = 0.f;
    if (j == 0) accs2[rk] = 0.f;
  } else {
    out_slots[rk * Dd + j] = sn;   // f32 output
  }
}

// ---------------- final: attn *= 1/S  (f32 RMW, float4)
__global__ __launch_bounds__(256) void scale_kernel(
    const float* __restrict__ accs, float* __restrict__ attn) {
  const size_t idx = ((size_t)blockIdx.x * 256 + threadIdx.x) * 4;
  const int bk = (int)(idx >> 12);   // / P
  const float inv = 1.f / accs[bk];
  float4 v = *(float4*)(attn + idx);
  v.x *= inv; v.y *= inv; v.z *= inv; v.w *= inv;
  *(float4*)(attn + idx) = v;
}

extern "C" void kernel_launch(void* const* d_in, const int* in_sizes, int n_in,
                              void* d_out, int out_size, void* d_ws, size_t ws_size,
                              hipStream_t stream) {
  const float* x      = (const float*)d_in[0];
  const float* noise  = (const float*)d_in[1];
  const float* smu    = (const float*)d_in[2];
  const float* ssig   = (const float*)d_in[3];
  const float* Wq     = (const float*)d_in[4];
  const float* Wk     = (const float*)d_in[5];
  const float* Wv     = (const float*)d_in[6];
  const float* W_ih   = (const float*)d_in[7];
  const float* W_hh   = (const float*)d_in[8];
  const float* b_ih   = (const float*)d_in[9];
  const float* b_hh   = (const float*)d_in[10];
  const float* ln_in_g = (const float*)d_in[11];
  const float* ln_in_b = (const float*)d_in[12];
  const float* ln_s_g  = (const float*)d_in[13];
  const float* ln_s_b  = (const float*)d_in[14];
  const float* ff_g   = (const float*)d_in[15];
  const float* ff_b   = (const float*)d_in[16];
  const float* W1     = (const float*)d_in[17];
  const float* b1     = (const float*)d_in[18];
  const float* W2     = (const float*)d_in[19];
  const float* b2     = (const float*)d_in[20];

  char* ws = (char*)d_ws;
  unsigned short* k_bf  = (unsigned short*)(ws);                    // 67,108,864 B
  unsigned short* vT_bf = (unsigned short*)(ws + 67108864);         // 67,108,864 B
  unsigned short* q_bf  = (unsigned short*)(ws + 134217728);        //    262,144 B
  float* slots = (float*)(ws + 134479872);                          //    262,144 B
  float* accu1 = (float*)(ws + 134742016);                          //    262,144 B
  float* accs1 = (float*)(ws + 135004160);                          //      4,096 B
  float* accu2 = (float*)(ws + 135008256);                          //    262,144 B
  float* accs2 = (float*)(ws + 135270400);                          //      4,096 B

  float* out_slots = (float*)d_out;                                 // [B,K,D] f32
  float* out_attn  = out_slots + (size_t)Bb * Kk * Dd;              // [B,K,P] f32

  init_kernel<<<dim3(Bb), dim3(512), 0, stream>>>(
      noise, smu, ssig, Wq, ln_s_g, ln_s_b, slots, q_bf, accu1, accs1);
  kv_kernel<<<dim3(Bb, 16), dim3(256), 0, stream>>>(
      x, Wk, Wv, ln_in_g, ln_in_b, k_bf, vT_bf);
  attn_kernel<false><<<dim3(Bb, 16), dim3(256), 0, stream>>>(
      q_bf, k_bf, vT_bf, accu1, accs1, nullptr);
  gru_kernel<false><<<dim3(Bb), dim3(512), 0, stream>>>(
      accu1, accs1, slots, W_ih, W_hh, b_ih, b_hh, ff_g, ff_b,
      W1, b1, W2, b2, ln_s_g, ln_s_b, Wq, q_bf, accu2, accs2, nullptr);
  attn_kernel<true><<<dim3(Bb, 16), dim3(256), 0, stream>>>(
      q_bf, k_bf, vT_bf, accu2, accs2, out_attn);
  gru_kernel<true><<<dim3(Bb), dim3(512), 0, stream>>>(
      accu2, accs2, slots, W_ih, W_hh, b_ih, b_hh, ff_g, ff_b,
      W1, b1, W2, b2, ln_s_g, ln_s_b, Wq, q_bf, accu2, accs2, out_slots);
  scale_kernel<<<dim3(4096), dim3(256), 0, stream>>>(accs2, out_attn);
}

// Round 3
// 298.696 us; speedup vs baseline: 1.4153x; 1.4153x over previous
//
#include <hip/hip_runtime.h>
#include <stdint.h>

#define Bb 128
#define Pp 4096
#define Ff 32
#define Kk 8
#define Dd 64

constexpr float EPS_ATTN_ = 1e-8f;
constexpr float EPS_LN_   = 1e-5f;
constexpr float SCALE_    = 0.125f;  // 64^-0.5

typedef __attribute__((ext_vector_type(8))) short short8;
typedef __attribute__((ext_vector_type(4))) short bfx4;
typedef __attribute__((ext_vector_type(4))) float floatx4;

__device__ __forceinline__ unsigned short f2bf(float f) {
  union { float f; unsigned u; } c; c.f = f;
  unsigned u = c.u + 0x7fffu + ((c.u >> 16) & 1u);  // RNE
  return (unsigned short)(u >> 16);
}
__device__ __forceinline__ float wsum(float v) {
  v += __shfl_xor(v, 1, 64);  v += __shfl_xor(v, 2, 64);
  v += __shfl_xor(v, 4, 64);  v += __shfl_xor(v, 8, 64);
  v += __shfl_xor(v, 16, 64); v += __shfl_xor(v, 32, 64);
  return v;
}

// ---------------- K0: slots0 = mu + |sigma|*noise ; q1 = LN(slots0)@Wq^T * SCALE ; zero acc1
__global__ __launch_bounds__(512) void init_kernel(
    const float* __restrict__ noise, const float* __restrict__ smu,
    const float* __restrict__ ssig, const float* __restrict__ Wq,
    const float* __restrict__ lsg, const float* __restrict__ lsb,
    float* __restrict__ slots, unsigned short* __restrict__ q_bf,
    float* __restrict__ accu, float* __restrict__ accs) {
  const int b = blockIdx.x;
  const int k = threadIdx.x >> 6;   // wave = slot
  const int j = threadIdx.x & 63;   // lane = d
  __shared__ float lnv[Kk][Dd];
  __shared__ float wq[64 * 65];     // LDS-staged Wq, pad 65 -> conflict-free row reads
  {
    const float4* g4 = (const float4*)Wq;
    #pragma unroll
    for (int i = 0; i < 2; ++i) {
      int f4i = threadIdx.x + i * 512;
      float4 v = g4[f4i];
      int fi = f4i * 4, row = fi >> 6, col = fi & 63;
      float* dst = &wq[row * 65 + col];
      dst[0] = v.x; dst[1] = v.y; dst[2] = v.z; dst[3] = v.w;
    }
  }
  const size_t rk = (size_t)b * Kk + k;
  float s0 = smu[j] + fabsf(ssig[j]) * noise[rk * Dd + j];
  slots[rk * Dd + j] = s0;
  float mu  = wsum(s0) * (1.f / 64.f);
  float dc  = s0 - mu;
  float var = wsum(dc * dc) * (1.f / 64.f);
  float xn  = dc * rsqrtf(var + EPS_LN_) * lsg[j] + lsb[j];
  lnv[k][j] = xn;
  __syncthreads();
  float q = 0.f;
  #pragma unroll 8
  for (int d = 0; d < Dd; ++d) q = fmaf(wq[j * 65 + d], lnv[k][d], q);
  q_bf[((size_t)b * 16 + k) * Dd + j]     = f2bf(q * SCALE_);
  q_bf[((size_t)b * 16 + k + 8) * Dd + j] = 0;   // zero-pad rows 8..15 (MFMA M=16)
  accu[rk * Dd + j] = 0.f;
  if (j == 0) accs[rk] = 0.f;
}

// ---------------- A: x -> LN -> k (pixel-major bf16), v (d-major bf16) — all-MFMA.
// F=32 == K of mfma_f32_16x16x32_bf16, so each 16-out x 16-px tile is ONE mfma (C=0).
// The same x-fragment registers serve as B (for k = Wk @ X^T) and A (for v = X @ Wv^T).
__global__ __launch_bounds__(256) void kv_kernel(
    const float* __restrict__ x, const float* __restrict__ Wk,
    const float* __restrict__ Wv, const float* __restrict__ lg,
    const float* __restrict__ lb, unsigned short* __restrict__ k_bf,
    unsigned short* __restrict__ vT_bf) {
  const int b  = blockIdx.x;
  const int p0 = blockIdx.y * 256;
  const int w    = threadIdx.x >> 6;
  const int lane = threadIdx.x & 63;
  const int m    = lane & 15;
  const int quad = lane >> 4;
  __shared__ float          xs[256 * 36];  // f32 staging, pad 36 (16B-aligned rows)
  __shared__ unsigned short xb[256 * 40];  // bf16 LN'd x, pad 40 shorts (80B rows)

  // stage A: coalesced x -> LDS
  const float4* xg = (const float4*)(x + ((size_t)b * Pp + p0) * Ff);
  #pragma unroll
  for (int i = 0; i < 8; ++i) {
    int f4i = threadIdx.x + i * 256;
    float4 v = xg[f4i];
    int px = f4i >> 3, c = (f4i & 7) * 4;
    *(float4*)&xs[px * 36 + c] = v;
  }
  __syncthreads();

  // stage B: per-thread LN (thread = pixel), write bf16 frag buffer
  {
    float xv[Ff];
    #pragma unroll
    for (int j4 = 0; j4 < 8; ++j4) {
      float4 t = *(const float4*)&xs[threadIdx.x * 36 + j4 * 4];
      xv[j4*4] = t.x; xv[j4*4+1] = t.y; xv[j4*4+2] = t.z; xv[j4*4+3] = t.w;
    }
    float mu = 0.f;
    #pragma unroll
    for (int j = 0; j < Ff; ++j) mu += xv[j];
    mu *= (1.f / Ff);
    float var = 0.f;
    #pragma unroll
    for (int j = 0; j < Ff; ++j) { float d = xv[j] - mu; var = fmaf(d, d, var); }
    var *= (1.f / Ff);
    float rr = rsqrtf(var + EPS_LN_);
    #pragma unroll
    for (int j = 0; j < Ff; ++j) xv[j] = (xv[j] - mu) * rr * lg[j] + lb[j];
    #pragma unroll
    for (int j8 = 0; j8 < 4; ++j8) {
      short8 pk;
      #pragma unroll
      for (int jj = 0; jj < 8; ++jj) pk[jj] = (short)f2bf(xv[j8 * 8 + jj]);
      *(short8*)&xb[threadIdx.x * 40 + j8 * 8] = pk;
    }
  }

  // stage C: weight frags (rows tile*16+m, cols quad*8..+7) — L2-hot, tiny
  short8 wkf[4], wvf[4];
  #pragma unroll
  for (int o = 0; o < 4; ++o) {
    const float* rkp = Wk + (size_t)(o * 16 + m) * Ff + quad * 8;
    const float* rvp = Wv + (size_t)(o * 16 + m) * Ff + quad * 8;
    float4 a0 = *(const float4*)(rkp), a1 = *(const float4*)(rkp + 4);
    float4 b0 = *(const float4*)(rvp), b1 = *(const float4*)(rvp + 4);
    short8 pk, pv;
    pk[0]=(short)f2bf(a0.x); pk[1]=(short)f2bf(a0.y); pk[2]=(short)f2bf(a0.z); pk[3]=(short)f2bf(a0.w);
    pk[4]=(short)f2bf(a1.x); pk[5]=(short)f2bf(a1.y); pk[6]=(short)f2bf(a1.z); pk[7]=(short)f2bf(a1.w);
    pv[0]=(short)f2bf(b0.x); pv[1]=(short)f2bf(b0.y); pv[2]=(short)f2bf(b0.z); pv[3]=(short)f2bf(b0.w);
    pv[4]=(short)f2bf(b1.x); pv[5]=(short)f2bf(b1.y); pv[6]=(short)f2bf(b1.z); pv[7]=(short)f2bf(b1.w);
    wkf[o] = pk; wvf[o] = pv;
  }
  __syncthreads();

  // stage D: x frags — x_norm[pixel = m (+t*16)][f = quad*8+j]
  short8 xf[4];
  #pragma unroll
  for (int t = 0; t < 4; ++t)
    xf[t] = *(const short8*)&xb[(w * 64 + t * 16 + m) * 40 + quad * 8];

  const floatx4 Z = {0.f, 0.f, 0.f, 0.f};
  // stage E: k tiles. C[row=d out][col=pixel] -> pack 4 d's (quad*4+r) per lane, 8B store.
  #pragma unroll
  for (int o = 0; o < 4; ++o) {
    #pragma unroll
    for (int t = 0; t < 4; ++t) {
      floatx4 C = __builtin_amdgcn_mfma_f32_16x16x32_bf16(wkf[o], xf[t], Z, 0, 0, 0);
      bfx4 pk;
      pk[0]=(short)f2bf(C[0]); pk[1]=(short)f2bf(C[1]);
      pk[2]=(short)f2bf(C[2]); pk[3]=(short)f2bf(C[3]);
      const size_t px = (size_t)b * Pp + p0 + w * 64 + t * 16 + m;
      *(bfx4*)(k_bf + px * Dd + o * 16 + quad * 4) = pk;
    }
  }
  // stage F: v tiles. C[row=pixel][col=d] -> pack 4 px's (quad*4+r) per lane, 8B store.
  #pragma unroll
  for (int t = 0; t < 4; ++t) {
    #pragma unroll
    for (int o = 0; o < 4; ++o) {
      floatx4 C = __builtin_amdgcn_mfma_f32_16x16x32_bf16(xf[t], wvf[o], Z, 0, 0, 0);
      bfx4 pv;
      pv[0]=(short)f2bf(C[0]); pv[1]=(short)f2bf(C[1]);
      pv[2]=(short)f2bf(C[2]); pv[3]=(short)f2bf(C[3]);
      const size_t dr = (size_t)b * Dd + o * 16 + m;
      *(bfx4*)(vT_bf + dr * Pp + p0 + w * 64 + t * 16 + quad * 4) = pv;
    }
  }
}

// ---------------- H: dots=q@k^T (MFMA) -> softmax over slots (+eps) -> acc += a@v (MFMA)
template <bool LAST>
__global__ __launch_bounds__(256) void attn_kernel(
    const unsigned short* __restrict__ q_bf,
    const unsigned short* __restrict__ k_bf,
    const unsigned short* __restrict__ vT_bf,
    float* __restrict__ accu, float* __restrict__ accs,
    float* __restrict__ attn_out) {
  const int b    = blockIdx.x;
  const int p0   = blockIdx.y * 256;
  const int w    = threadIdx.x >> 6;
  const int lane = threadIdx.x & 63;
  const int m    = lane & 15;
  const int quad = lane >> 4;
  __shared__ __align__(16) unsigned short A_lds[4][16][72];  // per-wave attn tile, +8 pad

  const unsigned short* qp = q_bf + ((size_t)b * 16 + m) * Dd + quad * 8;
  const short8 aq0 = *(const short8*)(qp);
  const short8 aq1 = *(const short8*)(qp + 32);

  float Ss0 = 0.f, Ss1 = 0.f, Ss2 = 0.f, Ss3 = 0.f;
  floatx4 Cg0 = {0.f,0.f,0.f,0.f}, Cg1 = {0.f,0.f,0.f,0.f},
          Cg2 = {0.f,0.f,0.f,0.f}, Cg3 = {0.f,0.f,0.f,0.f};

  const int pw = p0 + w * 64;
  #pragma unroll
  for (int t = 0; t < 4; ++t) {
    const int pt = pw + t * 16;
    const unsigned short* kp = k_bf + ((size_t)b * Pp + pt + m) * Dd + quad * 8;
    short8 bk0 = *(const short8*)(kp);
    short8 bk1 = *(const short8*)(kp + 32);
    floatx4 C = {0.f, 0.f, 0.f, 0.f};
    C = __builtin_amdgcn_mfma_f32_16x16x32_bf16(aq0, bk0, C, 0, 0, 0);
    C = __builtin_amdgcn_mfma_f32_16x16x32_bf16(aq1, bk1, C, 0, 0, 0);
    float mx = fmaxf(fmaxf(C[0], C[1]), fmaxf(C[2], C[3]));
    mx = fmaxf(mx, __shfl_xor(mx, 16, 64));
    float e0 = __expf(C[0] - mx), e1 = __expf(C[1] - mx),
          e2 = __expf(C[2] - mx), e3 = __expf(C[3] - mx);
    float s = e0 + e1 + e2 + e3;
    s += __shfl_xor(s, 16, 64);
    float inv = 1.f / s;
    float a0 = fmaf(e0, inv, EPS_ATTN_), a1 = fmaf(e1, inv, EPS_ATTN_);
    float a2 = fmaf(e2, inv, EPS_ATTN_), a3 = fmaf(e3, inv, EPS_ATTN_);
    Ss0 += a0; Ss1 += a1; Ss2 += a2; Ss3 += a3;
    unsigned short h0 = f2bf(a0), h1 = f2bf(a1), h2 = f2bf(a2), h3 = f2bf(a3);
    const int r0 = quad * 4;
    A_lds[w][r0 + 0][t * 16 + m] = h0;
    A_lds[w][r0 + 1][t * 16 + m] = h1;
    A_lds[w][r0 + 2][t * 16 + m] = h2;
    A_lds[w][r0 + 3][t * 16 + m] = h3;
    if (LAST && quad < 2) {
      float* ao = attn_out + ((size_t)b * Kk + r0) * Pp + pt + m;
      ao[0] = a0; ao[Pp] = a1; ao[2 * (size_t)Pp] = a2; ao[3 * (size_t)Pp] = a3;
    }
  }
  __syncthreads();
  #pragma unroll
  for (int ks = 0; ks < 2; ++ks) {
    const short8 af = *(const short8*)(&A_lds[w][m][ks * 32 + quad * 8]);
    const unsigned short* vb = vT_bf + (size_t)b * Dd * Pp + pw + ks * 32 + quad * 8;
    short8 bv0 = *(const short8*)(vb + (size_t)(m)      * Pp);
    short8 bv1 = *(const short8*)(vb + (size_t)(16 + m) * Pp);
    short8 bv2 = *(const short8*)(vb + (size_t)(32 + m) * Pp);
    short8 bv3 = *(const short8*)(vb + (size_t)(48 + m) * Pp);
    Cg0 = __builtin_amdgcn_mfma_f32_16x16x32_bf16(af, bv0, Cg0, 0, 0, 0);
    Cg1 = __builtin_amdgcn_mfma_f32_16x16x32_bf16(af, bv1, Cg1, 0, 0, 0);
    Cg2 = __builtin_amdgcn_mfma_f32_16x16x32_bf16(af, bv2, Cg2, 0, 0, 0);
    Cg3 = __builtin_amdgcn_mfma_f32_16x16x32_bf16(af, bv3, Cg3, 0, 0, 0);
  }
  Ss0 += __shfl_xor(Ss0,1,64); Ss0 += __shfl_xor(Ss0,2,64); Ss0 += __shfl_xor(Ss0,4,64); Ss0 += __shfl_xor(Ss0,8,64);
  Ss1 += __shfl_xor(Ss1,1,64); Ss1 += __shfl_xor(Ss1,2,64); Ss1 += __shfl_xor(Ss1,4,64); Ss1 += __shfl_xor(Ss1,8,64);
  Ss2 += __shfl_xor(Ss2,1,64); Ss2 += __shfl_xor(Ss2,2,64); Ss2 += __shfl_xor(Ss2,4,64); Ss2 += __shfl_xor(Ss2,8,64);
  Ss3 += __shfl_xor(Ss3,1,64); Ss3 += __shfl_xor(Ss3,2,64); Ss3 += __shfl_xor(Ss3,4,64); Ss3 += __shfl_xor(Ss3,8,64);
  if (quad < 2) {
    const int row = quad * 4;
    float* up = accu + ((size_t)b * Kk + row) * Dd + m;
    #pragma unroll
    for (int r = 0; r < 4; ++r) {
      atomicAdd(up + (size_t)r * Dd + 0,  Cg0[r]);
      atomicAdd(up + (size_t)r * Dd + 16, Cg1[r]);
      atomicAdd(up + (size_t)r * Dd + 32, Cg2[r]);
      atomicAdd(up + (size_t)r * Dd + 48, Cg3[r]);
    }
    if (m == 0) {
      atomicAdd(&accs[b * Kk + row + 0], Ss0);
      atomicAdd(&accs[b * Kk + row + 1], Ss1);
      atomicAdd(&accs[b * Kk + row + 2], Ss2);
      atomicAdd(&accs[b * Kk + row + 3], Ss3);
    }
  }
}

// ---------------- G: updates=U/S -> GRUCell -> +FF -> slots' ; next q (or final f32 out)
// 256 blocks (b x 2 slot-halves), all weights LDS-staged with anti-conflict padding.
template <bool LAST>
__global__ __launch_bounds__(256) void gru_kernel(
    const float* __restrict__ accu, const float* __restrict__ accs,
    float* __restrict__ slots,
    const float* __restrict__ W_ih, const float* __restrict__ W_hh,
    const float* __restrict__ b_ih, const float* __restrict__ b_hh,
    const float* __restrict__ fg, const float* __restrict__ fb,
    const float* __restrict__ W1, const float* __restrict__ b1,
    const float* __restrict__ W2, const float* __restrict__ b2,
    const float* __restrict__ lsg, const float* __restrict__ lsb,
    const float* __restrict__ Wq,
    unsigned short* __restrict__ q_bf,
    float* __restrict__ accu2, float* __restrict__ accs2,
    float* __restrict__ out_slots) {
  const int b = blockIdx.x;
  const int kh = blockIdx.y;            // slot half
  const int k = threadIdx.x >> 6;       // local slot 0..3
  const int j = threadIdx.x & 63;
  const int kg = kh * 4 + k;            // global slot
  __shared__ float WA[192 * 65];        // W_ih -> then W1 (128x65) + Wq (64x65 @8320)
  __shared__ float WB[192 * 65];        // W_hh -> then W2 (64x129)
  __shared__ float Ub[4][Dd];
  __shared__ float Hb[4][Dd];
  __shared__ float Tb[4][2 * Dd];
  // stage W_ih, W_hh (12288 floats each, coalesced)
  {
    const float4* gi = (const float4*)W_ih;
    const float4* gh = (const float4*)W_hh;
    #pragma unroll
    for (int i = 0; i < 12; ++i) {
      int f4i = threadIdx.x + i * 256;
      float4 vi = gi[f4i], vh = gh[f4i];
      int fi = f4i * 4, row = fi >> 6, col = fi & 63;
      float* da = &WA[row * 65 + col];
      float* db = &WB[row * 65 + col];
      da[0]=vi.x; da[1]=vi.y; da[2]=vi.z; da[3]=vi.w;
      db[0]=vh.x; db[1]=vh.y; db[2]=vh.z; db[3]=vh.w;
    }
  }
  const size_t rk = (size_t)b * Kk + kg;
  const float S = accs[rk];
  const float u = accu[rk * Dd + j] / S;
  const float h = slots[rk * Dd + j];
  Ub[k][j] = u;
  Hb[k][j] = h;
  __syncthreads();
  float gr = b_ih[j], gz = b_ih[64 + j], gn = b_ih[128 + j];
  float hr = b_hh[j], hz = b_hh[64 + j], hn_ = b_hh[128 + j];
  #pragma unroll 4
  for (int d = 0; d < Dd; ++d) {
    const float ud = Ub[k][d], hd = Hb[k][d];
    gr  = fmaf(WA[j * 65 + d],         ud, gr);
    gz  = fmaf(WA[(64 + j) * 65 + d],  ud, gz);
    gn  = fmaf(WA[(128 + j) * 65 + d], ud, gn);
    hr  = fmaf(WB[j * 65 + d],         hd, hr);
    hz  = fmaf(WB[(64 + j) * 65 + d],  hd, hz);
    hn_ = fmaf(WB[(128 + j) * 65 + d], hd, hn_);
  }
  const float r = 1.f / (1.f + __expf(-(gr + hr)));
  const float z = 1.f / (1.f + __expf(-(gz + hz)));
  const float n = tanhf(fmaf(r, hn_, gn));
  const float hnew = fmaf(z, h - n, n);    // (1-z)*n + z*h
  float mu  = wsum(hnew) * (1.f / 64.f);
  float dc  = hnew - mu;
  float var = wsum(dc * dc) * (1.f / 64.f);
  float fi_ = dc * rsqrtf(var + EPS_LN_) * fg[j] + fb[j];
  __syncthreads();   // all reads of WA/WB/Ub complete
  Ub[k][j] = fi_;
  // stage W1 (128x65), Wq (64x65 at +8320), W2 (64x129)
  {
    const float4* g1 = (const float4*)W1;
    #pragma unroll
    for (int i = 0; i < 8; ++i) {
      int f4i = threadIdx.x + i * 256;
      float4 v = g1[f4i];
      int fi = f4i * 4, row = fi >> 6, col = fi & 63;
      float* d_ = &WA[row * 65 + col];
      d_[0]=v.x; d_[1]=v.y; d_[2]=v.z; d_[3]=v.w;
    }
    const float4* gq = (const float4*)Wq;
    #pragma unroll
    for (int i = 0; i < 4; ++i) {
      int f4i = threadIdx.x + i * 256;
      float4 v = gq[f4i];
      int fi = f4i * 4, row = fi >> 6, col = fi & 63;
      float* d_ = &WA[8320 + row * 65 + col];
      d_[0]=v.x; d_[1]=v.y; d_[2]=v.z; d_[3]=v.w;
    }
    const float4* g2 = (const float4*)W2;
    #pragma unroll
    for (int i = 0; i < 8; ++i) {
      int f4i = threadIdx.x + i * 256;
      float4 v = g2[f4i];
      int fi = f4i * 4, row = fi >> 7, col = fi & 127;
      float* d_ = &WB[row * 129 + col];
      d_[0]=v.x; d_[1]=v.y; d_[2]=v.z; d_[3]=v.w;
    }
  }
  __syncthreads();
  float f1a = b1[j], f1b = b1[64 + j];
  #pragma unroll 4
  for (int d = 0; d < Dd; ++d) {
    const float t = Ub[k][d];
    f1a = fmaf(WA[j * 65 + d],        t, f1a);
    f1b = fmaf(WA[(64 + j) * 65 + d], t, f1b);
  }
  f1a = fmaxf(f1a, 0.f);
  f1b = fmaxf(f1b, 0.f);
  __syncthreads();   // f1 reads of Ub complete (Ub overwritten again below)
  Tb[k][j]      = f1a;
  Tb[k][64 + j] = f1b;
  __syncthreads();
  float o = b2[j];
  #pragma unroll 4
  for (int e = 0; e < 2 * Dd; ++e) o = fmaf(WB[j * 129 + e], Tb[k][e], o);
  const float sn = hnew + o;
  if (!LAST) {
    slots[rk * Dd + j] = sn;
    float mq = wsum(sn) * (1.f / 64.f);
    float dq = sn - mq;
    float vq = wsum(dq * dq) * (1.f / 64.f);
    float xq = dq * rsqrtf(vq + EPS_LN_) * lsg[j] + lsb[j];
    __syncthreads();
    Ub[k][j] = xq;
    __syncthreads();
    float q = 0.f;
    #pragma unroll 8
    for (int d = 0; d < Dd; ++d) q = fmaf(WA[8320 + j * 65 + d], Ub[k][d], q);
    q_bf[((size_t)b * 16 + kg) * Dd + j]     = f2bf(q * SCALE_);
    q_bf[((size_t)b * 16 + kg + 8) * Dd + j] = 0;
    accu2[rk * Dd + j] = 0.f;
    if (j == 0) accs2[rk] = 0.f;
  } else {
    out_slots[rk * Dd + j] = sn;
  }
}

// ---------------- final: attn *= 1/S  (f32 RMW, float4)
__global__ __launch_bounds__(256) void scale_kernel(
    const float* __restrict__ accs, float* __restrict__ attn) {
  const size_t idx = ((size_t)blockIdx.x * 256 + threadIdx.x) * 4;
  const int bk = (int)(idx >> 12);
  const float inv = 1.f / accs[bk];
  float4 v = *(float4*)(attn + idx);
  v.x *= inv; v.y *= inv; v.z *= inv; v.w *= inv;
  *(float4*)(attn + idx) = v;
}

extern "C" void kernel_launch(void* const* d_in, const int* in_sizes, int n_in,
                              void* d_out, int out_size, void* d_ws, size_t ws_size,
                              hipStream_t stream) {
  const float* x      = (const float*)d_in[0];
  const float* noise  = (const float*)d_in[1];
  const float* smu    = (const float*)d_in[2];
  const float* ssig   = (const float*)d_in[3];
  const float* Wq     = (const float*)d_in[4];
  const float* Wk     = (const float*)d_in[5];
  const float* Wv     = (const float*)d_in[6];
  const float* W_ih   = (const float*)d_in[7];
  const float* W_hh   = (const float*)d_in[8];
  const float* b_ih   = (const float*)d_in[9];
  const float* b_hh   = (const float*)d_in[10];
  const float* ln_in_g = (const float*)d_in[11];
  const float* ln_in_b = (const float*)d_in[12];
  const float* ln_s_g  = (const float*)d_in[13];
  const float* ln_s_b  = (const float*)d_in[14];
  const float* ff_g   = (const float*)d_in[15];
  const float* ff_b   = (const float*)d_in[16];
  const float* W1     = (const float*)d_in[17];
  const float* b1     = (const float*)d_in[18];
  const float* W2     = (const float*)d_in[19];
  const float* b2     = (const float*)d_in[20];

  char* ws = (char*)d_ws;
  unsigned short* k_bf  = (unsigned short*)(ws);                    // 67,108,864 B
  unsigned short* vT_bf = (unsigned short*)(ws + 67108864);         // 67,108,864 B
  unsigned short* q_bf  = (unsigned short*)(ws + 134217728);        //    262,144 B
  float* slots = (float*)(ws + 134479872);
  float* accu1 = (float*)(ws + 134742016);
  float* accs1 = (float*)(ws + 135004160);
  float* accu2 = (float*)(ws + 135008256);
  float* accs2 = (float*)(ws + 135270400);

  float* out_slots = (float*)d_out;                                 // [B,K,D] f32
  float* out_attn  = out_slots + (size_t)Bb * Kk * Dd;              // [B,K,P] f32

  init_kernel<<<dim3(Bb), dim3(512), 0, stream>>>(
      noise, smu, ssig, Wq, ln_s_g, ln_s_b, slots, q_bf, accu1, accs1);
  kv_kernel<<<dim3(Bb, 16), dim3(256), 0, stream>>>(
      x, Wk, Wv, ln_in_g, ln_in_b, k_bf, vT_bf);
  attn_kernel<false><<<dim3(Bb, 16), dim3(256), 0, stream>>>(
      q_bf, k_bf, vT_bf, accu1, accs1, nullptr);
  gru_kernel<false><<<dim3(Bb, 2), dim3(256), 0, stream>>>(
      accu1, accs1, slots, W_ih, W_hh, b_ih, b_hh, ff_g, ff_b,
      W1, b1, W2, b2, ln_s_g, ln_s_b, Wq, q_bf, accu2, accs2, nullptr);
  attn_kernel<true><<<dim3(Bb, 16), dim3(256), 0, stream>>>(
      q_bf, k_bf, vT_bf, accu2, accs2, out_attn);
  gru_kernel<true><<<dim3(Bb, 2), dim3(256), 0, stream>>>(
      accu2, accs2, slots, W_ih, W_hh, b_ih, b_hh, ff_g, ff_b,
      W1, b1, W2, b2, ln_s_g, ln_s_b, Wq, q_bf, accu2, accs2, out_slots);
  scale_kernel<<<dim3(4096), dim3(256), 0, stream>>>(accs2, out_attn);
}

// Round 4
// 214.624 us; speedup vs baseline: 1.9697x; 1.3917x over previous
//
#include <hip/hip_runtime.h>
#include <stdint.h>

#define Bb 128
#define Pp 4096
#define Ff 32
#define Kk 8
#define Dd 64

constexpr float EPS_ATTN_ = 1e-8f;
constexpr float EPS_LN_   = 1e-5f;
constexpr float SCALE_    = 0.125f;  // 64^-0.5

typedef __attribute__((ext_vector_type(8))) short short8;
typedef __attribute__((ext_vector_type(4))) float floatx4;

__device__ __forceinline__ unsigned short f2bf(float f) {
  union { float f; unsigned u; } c; c.f = f;
  unsigned u = c.u + 0x7fffu + ((c.u >> 16) & 1u);  // RNE
  return (unsigned short)(u >> 16);
}
__device__ __forceinline__ float wsum(float v) {
  v += __shfl_xor(v, 1, 64);  v += __shfl_xor(v, 2, 64);
  v += __shfl_xor(v, 4, 64);  v += __shfl_xor(v, 8, 64);
  v += __shfl_xor(v, 16, 64); v += __shfl_xor(v, 32, 64);
  return v;
}

// ---------------- K0: slots0 = mu+|sigma|*noise ; q~ = SCALE*(LN(slots0)@Wq^T)@Wk ; zero acc
__global__ __launch_bounds__(512) void init_kernel(
    const float* __restrict__ noise, const float* __restrict__ smu,
    const float* __restrict__ ssig, const float* __restrict__ Wq,
    const float* __restrict__ Wk,
    const float* __restrict__ lsg, const float* __restrict__ lsb,
    float* __restrict__ slots, unsigned short* __restrict__ qt_bf,
    float* __restrict__ acc_t, float* __restrict__ accs) {
  const int b = blockIdx.x;
  const int k = threadIdx.x >> 6;   // wave = slot
  const int j = threadIdx.x & 63;   // lane = d
  __shared__ float lnv[Kk][Dd];
  __shared__ float wq[64 * 65];     // Wq staged, pad 65
  __shared__ float wk[64 * 33];     // Wk staged [d][f], pad 33
  {
    const float4* g4 = (const float4*)Wq;
    #pragma unroll
    for (int i = 0; i < 2; ++i) {
      int f4i = threadIdx.x + i * 512;
      float4 v = g4[f4i];
      int fi = f4i * 4, row = fi >> 6, col = fi & 63;
      float* dst = &wq[row * 65 + col];
      dst[0] = v.x; dst[1] = v.y; dst[2] = v.z; dst[3] = v.w;
    }
    const float4* gk = (const float4*)Wk;   // 2048 floats = 512 float4
    float4 v = gk[threadIdx.x];
    int fi = threadIdx.x * 4, row = fi >> 5, col = fi & 31;
    float* dst = &wk[row * 33 + col];
    dst[0] = v.x; dst[1] = v.y; dst[2] = v.z; dst[3] = v.w;
  }
  const size_t rk = (size_t)b * Kk + k;
  float s0 = smu[j] + fabsf(ssig[j]) * noise[rk * Dd + j];
  slots[rk * Dd + j] = s0;
  float mu  = wsum(s0) * (1.f / 64.f);
  float dc  = s0 - mu;
  float var = wsum(dc * dc) * (1.f / 64.f);
  float xn  = dc * rsqrtf(var + EPS_LN_) * lsg[j] + lsb[j];
  lnv[k][j] = xn;
  __syncthreads();
  float q = 0.f;
  #pragma unroll 8
  for (int d = 0; d < Dd; ++d) q = fmaf(wq[j * 65 + d], lnv[k][d], q);
  __syncthreads();
  lnv[k][j] = q * SCALE_;          // reuse lnv for scaled q
  __syncthreads();
  if (j < Ff) {                    // q~[k][f=j] = sum_d q[d]*Wk[d][f]
    float qt = 0.f;
    #pragma unroll 8
    for (int d = 0; d < Dd; ++d) qt = fmaf(lnv[k][d], wk[d * 33 + j], qt);
    qt_bf[((size_t)b * 16 + k) * Ff + j]     = f2bf(qt);
    qt_bf[((size_t)b * 16 + k + 8) * Ff + j] = 0;   // zero rows 8..15 (MFMA M=16)
    acc_t[rk * Ff + j] = 0.f;
  }
  if (j == 0) accs[rk] = 0.f;
}

// ---------------- fused attention: x-strip -> LN -> dots = q~ . xn^T (1 MFMA/tile)
// -> softmax over slots -> acc_t[slot][f] += attn @ xn  (Wv applied later in gru).
// No k/v materialization at all.
template <bool LAST>
__global__ __launch_bounds__(256) void fattn_kernel(
    const float* __restrict__ x, const unsigned short* __restrict__ qt_bf,
    const float* __restrict__ lg, const float* __restrict__ lb,
    float* __restrict__ acc_t, float* __restrict__ accs,
    float* __restrict__ attn_out) {
  const int b  = blockIdx.x;
  const int p0 = blockIdx.y * 256;
  const int w    = threadIdx.x >> 6;
  const int lane = threadIdx.x & 63;
  const int m    = lane & 15;
  const int quad = lane >> 4;
  // one 36864B region, three lives:
  //  [0..36864) xs: f32 x staging [256][36]
  //  then [0..20480) xb: bf16 LN'd x [256][40] ; [20480..29696) A_lds [4][16][72]
  __shared__ __align__(16) char smem[36864];
  float* xs = (float*)smem;
  unsigned short* xb = (unsigned short*)smem;
  unsigned short (*A_lds)[16][72] = (unsigned short (*)[16][72])(smem + 20480);

  // stage x coalesced -> LDS (load all 8 first for MLP-friendly issue)
  {
    const float4* xg4 = (const float4*)(x + ((size_t)b * Pp + p0) * Ff);
    float4 st[8];
    #pragma unroll
    for (int i = 0; i < 8; ++i) st[i] = xg4[threadIdx.x + i * 256];
    #pragma unroll
    for (int i = 0; i < 8; ++i) {
      int f4i = threadIdx.x + i * 256;
      int px = f4i >> 3, c = (f4i & 7) * 4;
      *(float4*)&xs[px * 36 + c] = st[i];
    }
  }
  __syncthreads();
  // per-thread LN (thread = pixel) into registers
  short8 pk[4];
  {
    float xv[Ff];
    #pragma unroll
    for (int j4 = 0; j4 < 8; ++j4) {
      float4 t = *(const float4*)&xs[threadIdx.x * 36 + j4 * 4];
      xv[j4*4] = t.x; xv[j4*4+1] = t.y; xv[j4*4+2] = t.z; xv[j4*4+3] = t.w;
    }
    float mu = 0.f;
    #pragma unroll
    for (int j = 0; j < Ff; ++j) mu += xv[j];
    mu *= (1.f / Ff);
    float var = 0.f;
    #pragma unroll
    for (int j = 0; j < Ff; ++j) { float d = xv[j] - mu; var = fmaf(d, d, var); }
    var *= (1.f / Ff);
    float rr = rsqrtf(var + EPS_LN_);
    #pragma unroll
    for (int j = 0; j < Ff; ++j) xv[j] = (xv[j] - mu) * rr * lg[j] + lb[j];
    #pragma unroll
    for (int j8 = 0; j8 < 4; ++j8)
      #pragma unroll
      for (int jj = 0; jj < 8; ++jj) pk[j8][jj] = (short)f2bf(xv[j8 * 8 + jj]);
  }
  // q~ frag: A[slot=m][f=quad*8+j] (rows 8..15 are zero)
  const short8 aq = *(const short8*)(qt_bf + ((size_t)b * 16 + m) * Ff + quad * 8);
  __syncthreads();   // all xs reads done -> safe to overwrite region as xb
  #pragma unroll
  for (int j8 = 0; j8 < 4; ++j8)
    *(short8*)&xb[threadIdx.x * 40 + j8 * 8] = pk[j8];
  __syncthreads();

  float Ss0 = 0.f, Ss1 = 0.f, Ss2 = 0.f, Ss3 = 0.f;
  // ---- phase 1: dots (1 MFMA per 16-px tile, K=F=32) + softmax over slots
  #pragma unroll
  for (int t = 0; t < 4; ++t) {
    const int lpx = w * 64 + t * 16 + m;   // local pixel for B-frag
    const short8 bx = *(const short8*)&xb[lpx * 40 + quad * 8];
    floatx4 C = {0.f, 0.f, 0.f, 0.f};
    C = __builtin_amdgcn_mfma_f32_16x16x32_bf16(aq, bx, C, 0, 0, 0);
    // C: col=m=pixel, row=quad*4+r=slot; slot pairs in lanes {l, l^16}
    float mx = fmaxf(fmaxf(C[0], C[1]), fmaxf(C[2], C[3]));
    mx = fmaxf(mx, __shfl_xor(mx, 16, 64));
    float e0 = __expf(C[0] - mx), e1 = __expf(C[1] - mx),
          e2 = __expf(C[2] - mx), e3 = __expf(C[3] - mx);
    float s = e0 + e1 + e2 + e3;
    s += __shfl_xor(s, 16, 64);
    float inv = 1.f / s;
    float a0 = fmaf(e0, inv, EPS_ATTN_), a1 = fmaf(e1, inv, EPS_ATTN_);
    float a2 = fmaf(e2, inv, EPS_ATTN_), a3 = fmaf(e3, inv, EPS_ATTN_);
    Ss0 += a0; Ss1 += a1; Ss2 += a2; Ss3 += a3;
    const int r0 = quad * 4;   // quads 2,3 -> rows 8..15 (benign: uniform 0.125)
    A_lds[w][r0 + 0][t * 16 + m] = f2bf(a0);
    A_lds[w][r0 + 1][t * 16 + m] = f2bf(a1);
    A_lds[w][r0 + 2][t * 16 + m] = f2bf(a2);
    A_lds[w][r0 + 3][t * 16 + m] = f2bf(a3);
    if (LAST && quad < 2) {
      float* ao = attn_out + ((size_t)b * Kk + r0) * Pp + p0 + w * 64 + t * 16 + m;
      ao[0] = a0; ao[Pp] = a1; ao[2 * (size_t)Pp] = a2; ao[3 * (size_t)Pp] = a3;
    }
  }
  __syncthreads();
  // ---- phase 2: acc_t[slot][f] += attn @ xn  (A from A_lds, B = xn^T gathered from xb)
  floatx4 Cg0 = {0.f,0.f,0.f,0.f}, Cg1 = {0.f,0.f,0.f,0.f};
  #pragma unroll
  for (int ks = 0; ks < 2; ++ks) {
    const short8 af = *(const short8*)(&A_lds[w][m][ks * 32 + quad * 8]);
    const unsigned short* bp = xb + (size_t)(w * 64 + ks * 32 + quad * 8) * 40 + m;
    short8 xg0, xg1;
    #pragma unroll
    for (int jj = 0; jj < 8; ++jj) xg0[jj] = (short)bp[jj * 40];        // f = m
    #pragma unroll
    for (int jj = 0; jj < 8; ++jj) xg1[jj] = (short)bp[jj * 40 + 16];   // f = 16+m
    Cg0 = __builtin_amdgcn_mfma_f32_16x16x32_bf16(af, xg0, Cg0, 0, 0, 0);
    Cg1 = __builtin_amdgcn_mfma_f32_16x16x32_bf16(af, xg1, Cg1, 0, 0, 0);
  }
  // ---- epilogue
  Ss0 += __shfl_xor(Ss0,1,64); Ss0 += __shfl_xor(Ss0,2,64); Ss0 += __shfl_xor(Ss0,4,64); Ss0 += __shfl_xor(Ss0,8,64);
  Ss1 += __shfl_xor(Ss1,1,64); Ss1 += __shfl_xor(Ss1,2,64); Ss1 += __shfl_xor(Ss1,4,64); Ss1 += __shfl_xor(Ss1,8,64);
  Ss2 += __shfl_xor(Ss2,1,64); Ss2 += __shfl_xor(Ss2,2,64); Ss2 += __shfl_xor(Ss2,4,64); Ss2 += __shfl_xor(Ss2,8,64);
  Ss3 += __shfl_xor(Ss3,1,64); Ss3 += __shfl_xor(Ss3,2,64); Ss3 += __shfl_xor(Ss3,4,64); Ss3 += __shfl_xor(Ss3,8,64);
  if (quad < 2) {
    const int row = quad * 4;
    float* tp = acc_t + ((size_t)b * Kk + row) * Ff + m;
    #pragma unroll
    for (int r = 0; r < 4; ++r) {
      atomicAdd(tp + (size_t)r * Ff,      Cg0[r]);
      atomicAdd(tp + (size_t)r * Ff + 16, Cg1[r]);
    }
    if (m == 0) {
      atomicAdd(&accs[b * Kk + row + 0], Ss0);
      atomicAdd(&accs[b * Kk + row + 1], Ss1);
      atomicAdd(&accs[b * Kk + row + 2], Ss2);
      atomicAdd(&accs[b * Kk + row + 3], Ss3);
    }
  }
}

// ---------------- G: u = (acc_t @ Wv^T)/S -> GRUCell -> +FF -> slots' ; next q~ (or f32 out)
template <bool LAST>
__global__ __launch_bounds__(256) void gru_kernel(
    const float* __restrict__ acc_t, const float* __restrict__ accs,
    float* __restrict__ slots,
    const float* __restrict__ W_ih, const float* __restrict__ W_hh,
    const float* __restrict__ b_ih, const float* __restrict__ b_hh,
    const float* __restrict__ fg, const float* __restrict__ fb,
    const float* __restrict__ W1, const float* __restrict__ b1,
    const float* __restrict__ W2, const float* __restrict__ b2,
    const float* __restrict__ lsg, const float* __restrict__ lsb,
    const float* __restrict__ Wq, const float* __restrict__ Wv,
    const float* __restrict__ Wk,
    unsigned short* __restrict__ qt_bf,
    float* __restrict__ acc_t2, float* __restrict__ accs2,
    float* __restrict__ out_slots) {
  const int b = blockIdx.x;
  const int kh = blockIdx.y;            // slot half
  const int k = threadIdx.x >> 6;       // local slot 0..3
  const int j = threadIdx.x & 63;
  const int kg = kh * 4 + k;            // global slot
  __shared__ float WA[192 * 65];        // W_ih -> then W1 (128x65) + Wq (64x65 @8320)
  __shared__ float WB[192 * 65];        // W_hh -> then W2 (64x129)
  __shared__ float WVs[64 * 33];
  __shared__ float WKs[64 * 33];
  __shared__ float At[4][Ff];
  __shared__ float Ub[4][Dd];
  __shared__ float Hb[4][Dd];
  __shared__ float Tb[4][2 * Dd];
  __shared__ float qs[4][Dd];
  {
    const float4* gi = (const float4*)W_ih;
    const float4* gh = (const float4*)W_hh;
    #pragma unroll
    for (int i = 0; i < 12; ++i) {
      int f4i = threadIdx.x + i * 256;
      float4 vi = gi[f4i], vh = gh[f4i];
      int fi = f4i * 4, row = fi >> 6, col = fi & 63;
      float* da = &WA[row * 65 + col];
      float* db = &WB[row * 65 + col];
      da[0]=vi.x; da[1]=vi.y; da[2]=vi.z; da[3]=vi.w;
      db[0]=vh.x; db[1]=vh.y; db[2]=vh.z; db[3]=vh.w;
    }
    const float4* gv = (const float4*)Wv;
    #pragma unroll
    for (int i = 0; i < 2; ++i) {
      int f4i = threadIdx.x + i * 256;
      float4 v = gv[f4i];
      int fi = f4i * 4, row = fi >> 5, col = fi & 31;
      float* d_ = &WVs[row * 33 + col];
      d_[0]=v.x; d_[1]=v.y; d_[2]=v.z; d_[3]=v.w;
    }
    if (!LAST) {
      const float4* gk = (const float4*)Wk;
      #pragma unroll
      for (int i = 0; i < 2; ++i) {
        int f4i = threadIdx.x + i * 256;
        float4 v = gk[f4i];
        int fi = f4i * 4, row = fi >> 5, col = fi & 31;
        float* d_ = &WKs[row * 33 + col];
        d_[0]=v.x; d_[1]=v.y; d_[2]=v.z; d_[3]=v.w;
      }
    }
  }
  const size_t rk = (size_t)b * Kk + kg;
  const float S = accs[rk];
  if (j < Ff) At[k][j] = acc_t[rk * Ff + j];
  const float h = slots[rk * Dd + j];
  Hb[k][j] = h;
  __syncthreads();
  // u_d = (sum_f acc_t[f] * Wv[d][f]) / S
  float u = 0.f;
  #pragma unroll 8
  for (int f = 0; f < Ff; ++f) u = fmaf(WVs[j * 33 + f], At[k][f], u);
  u /= S;
  Ub[k][j] = u;
  __syncthreads();
  float gr = b_ih[j], gz = b_ih[64 + j], gn = b_ih[128 + j];
  float hr = b_hh[j], hz = b_hh[64 + j], hn_ = b_hh[128 + j];
  #pragma unroll 4
  for (int d = 0; d < Dd; ++d) {
    const float ud = Ub[k][d], hd = Hb[k][d];
    gr  = fmaf(WA[j * 65 + d],         ud, gr);
    gz  = fmaf(WA[(64 + j) * 65 + d],  ud, gz);
    gn  = fmaf(WA[(128 + j) * 65 + d], ud, gn);
    hr  = fmaf(WB[j * 65 + d],         hd, hr);
    hz  = fmaf(WB[(64 + j) * 65 + d],  hd, hz);
    hn_ = fmaf(WB[(128 + j) * 65 + d], hd, hn_);
  }
  const float r = 1.f / (1.f + __expf(-(gr + hr)));
  const float z = 1.f / (1.f + __expf(-(gz + hz)));
  const float n = tanhf(fmaf(r, hn_, gn));
  const float hnew = fmaf(z, h - n, n);    // (1-z)*n + z*h
  float mu  = wsum(hnew) * (1.f / 64.f);
  float dc  = hnew - mu;
  float var = wsum(dc * dc) * (1.f / 64.f);
  float fi_ = dc * rsqrtf(var + EPS_LN_) * fg[j] + fb[j];
  __syncthreads();   // all reads of WA/WB/Ub done
  Ub[k][j] = fi_;
  {
    const float4* g1 = (const float4*)W1;
    #pragma unroll
    for (int i = 0; i < 8; ++i) {
      int f4i = threadIdx.x + i * 256;
      float4 v = g1[f4i];
      int fi = f4i * 4, row = fi >> 6, col = fi & 63;
      float* d_ = &WA[row * 65 + col];
      d_[0]=v.x; d_[1]=v.y; d_[2]=v.z; d_[3]=v.w;
    }
    if (!LAST) {
      const float4* gq = (const float4*)Wq;
      #pragma unroll
      for (int i = 0; i < 4; ++i) {
        int f4i = threadIdx.x + i * 256;
        float4 v = gq[f4i];
        int fi = f4i * 4, row = fi >> 6, col = fi & 63;
        float* d_ = &WA[8320 + row * 65 + col];
        d_[0]=v.x; d_[1]=v.y; d_[2]=v.z; d_[3]=v.w;
      }
    }
    const float4* g2 = (const float4*)W2;
    #pragma unroll
    for (int i = 0; i < 8; ++i) {
      int f4i = threadIdx.x + i * 256;
      float4 v = g2[f4i];
      int fi = f4i * 4, row = fi >> 7, col = fi & 127;
      float* d_ = &WB[row * 129 + col];
      d_[0]=v.x; d_[1]=v.y; d_[2]=v.z; d_[3]=v.w;
    }
  }
  __syncthreads();
  float f1a = b1[j], f1b = b1[64 + j];
  #pragma unroll 4
  for (int d = 0; d < Dd; ++d) {
    const float t = Ub[k][d];
    f1a = fmaf(WA[j * 65 + d],        t, f1a);
    f1b = fmaf(WA[(64 + j) * 65 + d], t, f1b);
  }
  f1a = fmaxf(f1a, 0.f);
  f1b = fmaxf(f1b, 0.f);
  Tb[k][j]      = f1a;
  Tb[k][64 + j] = f1b;
  __syncthreads();
  float o = b2[j];
  #pragma unroll 4
  for (int e = 0; e < 2 * Dd; ++e) o = fmaf(WB[j * 129 + e], Tb[k][e], o);
  const float sn = hnew + o;
  if (!LAST) {
    slots[rk * Dd + j] = sn;
    float mq = wsum(sn) * (1.f / 64.f);
    float dq = sn - mq;
    float vq = wsum(dq * dq) * (1.f / 64.f);
    float xq = dq * rsqrtf(vq + EPS_LN_) * lsg[j] + lsb[j];
    Ub[k][j] = xq;      // Ub reads all done before Tb barrier
    __syncthreads();
    float q = 0.f;
    #pragma unroll 8
    for (int d = 0; d < Dd; ++d) q = fmaf(WA[8320 + j * 65 + d], Ub[k][d], q);
    qs[k][j] = q * SCALE_;
    __syncthreads();
    if (j < Ff) {
      float qt = 0.f;
      #pragma unroll 8
      for (int d = 0; d < Dd; ++d) qt = fmaf(qs[k][d], WKs[d * 33 + j], qt);
      qt_bf[((size_t)b * 16 + kg) * Ff + j]     = f2bf(qt);
      qt_bf[((size_t)b * 16 + kg + 8) * Ff + j] = 0;
      acc_t2[rk * Ff + j] = 0.f;
    }
    if (j == 0) accs2[rk] = 0.f;
  } else {
    out_slots[rk * Dd + j] = sn;
  }
}

// ---------------- final: attn *= 1/S  (f32 RMW, float4)
__global__ __launch_bounds__(256) void scale_kernel(
    const float* __restrict__ accs, float* __restrict__ attn) {
  const size_t idx = ((size_t)blockIdx.x * 256 + threadIdx.x) * 4;
  const int bk = (int)(idx >> 12);
  const float inv = 1.f / accs[bk];
  float4 v = *(float4*)(attn + idx);
  v.x *= inv; v.y *= inv; v.z *= inv; v.w *= inv;
  *(float4*)(attn + idx) = v;
}

extern "C" void kernel_launch(void* const* d_in, const int* in_sizes, int n_in,
                              void* d_out, int out_size, void* d_ws, size_t ws_size,
                              hipStream_t stream) {
  const float* x      = (const float*)d_in[0];
  const float* noise  = (const float*)d_in[1];
  const float* smu    = (const float*)d_in[2];
  const float* ssig   = (const float*)d_in[3];
  const float* Wq     = (const float*)d_in[4];
  const float* Wk     = (const float*)d_in[5];
  const float* Wv     = (const float*)d_in[6];
  const float* W_ih   = (const float*)d_in[7];
  const float* W_hh   = (const float*)d_in[8];
  const float* b_ih   = (const float*)d_in[9];
  const float* b_hh   = (const float*)d_in[10];
  const float* ln_in_g = (const float*)d_in[11];
  const float* ln_in_b = (const float*)d_in[12];
  const float* ln_s_g  = (const float*)d_in[13];
  const float* ln_s_b  = (const float*)d_in[14];
  const float* ff_g   = (const float*)d_in[15];
  const float* ff_b   = (const float*)d_in[16];
  const float* W1     = (const float*)d_in[17];
  const float* b1     = (const float*)d_in[18];
  const float* W2     = (const float*)d_in[19];
  const float* b2     = (const float*)d_in[20];

  char* ws = (char*)d_ws;
  unsigned short* qt_bf = (unsigned short*)(ws);        // 131,072 B
  float* slots  = (float*)(ws + 131072);                // 262,144 B
  float* acc_t1 = (float*)(ws + 393216);                // 131,072 B
  float* accs1  = (float*)(ws + 524288);                //   4,096 B
  float* acc_t2 = (float*)(ws + 528384);                // 131,072 B
  float* accs2  = (float*)(ws + 659456);                //   4,096 B

  float* out_slots = (float*)d_out;                     // [B,K,D] f32
  float* out_attn  = out_slots + (size_t)Bb * Kk * Dd;  // [B,K,P] f32

  init_kernel<<<dim3(Bb), dim3(512), 0, stream>>>(
      noise, smu, ssig, Wq, Wk, ln_s_g, ln_s_b, slots, qt_bf, acc_t1, accs1);
  fattn_kernel<false><<<dim3(Bb, 16), dim3(256), 0, stream>>>(
      x, qt_bf, ln_in_g, ln_in_b, acc_t1, accs1, nullptr);
  gru_kernel<false><<<dim3(Bb, 2), dim3(256), 0, stream>>>(
      acc_t1, accs1, slots, W_ih, W_hh, b_ih, b_hh, ff_g, ff_b,
      W1, b1, W2, b2, ln_s_g, ln_s_b, Wq, Wv, Wk, qt_bf, acc_t2, accs2, nullptr);
  fattn_kernel<true><<<dim3(Bb, 16), dim3(256), 0, stream>>>(
      x, qt_bf, ln_in_g, ln_in_b, acc_t2, accs2, out_attn);
  gru_kernel<true><<<dim3(Bb, 2), dim3(256), 0, stream>>>(
      acc_t2, accs2, slots, W_ih, W_hh, b_ih, b_hh, ff_g, ff_b,
      W1, b1, W2, b2, ln_s_g, ln_s_b, Wq, Wv, Wk, qt_bf, acc_t2, accs2, out_slots);
  scale_kernel<<<dim3(4096), dim3(256), 0, stream>>>(accs2, out_attn);
}

// Round 5
// 201.007 us; speedup vs baseline: 2.1031x; 1.0677x over previous
//
#include <hip/hip_runtime.h>
#include <stdint.h>

#define Bb 128
#define Pp 4096
#define Ff 32
#define Kk 8
#define Dd 64

constexpr float EPS_ATTN_ = 1e-8f;
constexpr float EPS_LN_   = 1e-5f;
constexpr float SCALE_    = 0.125f;  // 64^-0.5

typedef __attribute__((ext_vector_type(8))) short short8;
typedef __attribute__((ext_vector_type(4))) float floatx4;

__device__ __forceinline__ unsigned short f2bf(float f) {
  union { float f; unsigned u; } c; c.f = f;
  unsigned u = c.u + 0x7fffu + ((c.u >> 16) & 1u);  // RNE
  return (unsigned short)(u >> 16);
}
__device__ __forceinline__ float wsum(float v) {
  v += __shfl_xor(v, 1, 64);  v += __shfl_xor(v, 2, 64);
  v += __shfl_xor(v, 4, 64);  v += __shfl_xor(v, 8, 64);
  v += __shfl_xor(v, 16, 64); v += __shfl_xor(v, 32, 64);
  return v;
}

// ---------------- K0: slots0 = mu+|sigma|*noise ; q~ = SCALE*(LN(slots0)@Wq^T)@Wk ; zero acc
__global__ __launch_bounds__(512) void init_kernel(
    const float* __restrict__ noise, const float* __restrict__ smu,
    const float* __restrict__ ssig, const float* __restrict__ Wq,
    const float* __restrict__ Wk,
    const float* __restrict__ lsg, const float* __restrict__ lsb,
    float* __restrict__ slots, unsigned short* __restrict__ qt_bf,
    float* __restrict__ acc_t, float* __restrict__ accs) {
  const int b = blockIdx.x;
  const int k = threadIdx.x >> 6;   // wave = slot
  const int j = threadIdx.x & 63;   // lane = d
  __shared__ float lnv[Kk][Dd];
  __shared__ float wq[64 * 65];     // Wq staged, pad 65
  __shared__ float wk[64 * 33];     // Wk staged [d][f], pad 33
  {
    const float4* g4 = (const float4*)Wq;
    #pragma unroll
    for (int i = 0; i < 2; ++i) {
      int f4i = threadIdx.x + i * 512;
      float4 v = g4[f4i];
      int fi = f4i * 4, row = fi >> 6, col = fi & 63;
      float* dst = &wq[row * 65 + col];
      dst[0] = v.x; dst[1] = v.y; dst[2] = v.z; dst[3] = v.w;
    }
    const float4* gk = (const float4*)Wk;   // 2048 floats = 512 float4
    float4 v = gk[threadIdx.x];
    int fi = threadIdx.x * 4, row = fi >> 5, col = fi & 31;
    float* dst = &wk[row * 33 + col];
    dst[0] = v.x; dst[1] = v.y; dst[2] = v.z; dst[3] = v.w;
  }
  const size_t rk = (size_t)b * Kk + k;
  float s0 = smu[j] + fabsf(ssig[j]) * noise[rk * Dd + j];
  slots[rk * Dd + j] = s0;
  float mu  = wsum(s0) * (1.f / 64.f);
  float dc  = s0 - mu;
  float var = wsum(dc * dc) * (1.f / 64.f);
  float xn  = dc * rsqrtf(var + EPS_LN_) * lsg[j] + lsb[j];
  lnv[k][j] = xn;
  __syncthreads();
  float q = 0.f;
  #pragma unroll 8
  for (int d = 0; d < Dd; ++d) q = fmaf(wq[j * 65 + d], lnv[k][d], q);
  __syncthreads();
  lnv[k][j] = q * SCALE_;          // reuse lnv for scaled q
  __syncthreads();
  if (j < Ff) {                    // q~[k][f=j] = sum_d q[d]*Wk[d][f]
    float qt = 0.f;
    #pragma unroll 8
    for (int d = 0; d < Dd; ++d) qt = fmaf(lnv[k][d], wk[d * 33 + j], qt);
    qt_bf[((size_t)b * 16 + k) * Ff + j]     = f2bf(qt);
    qt_bf[((size_t)b * 16 + k + 8) * Ff + j] = 0;   // zero rows 8..15 (MFMA M=16)
    acc_t[rk * Ff + j] = 0.f;
  }
  if (j == 0) accs[rk] = 0.f;
}

// ---------------- fused attention: x-strip -> LN -> dots = q~ . xn^T (1 MFMA/tile)
// -> softmax over slots -> acc_t[slot][f] += attn @ xn  (Wv applied later in gru).
// 2 rounds of 256 px per block; Cg/Ss accumulate in registers across rounds.
#define ROUNDS 2
template <bool LAST>
__global__ __launch_bounds__(256) void fattn_kernel(
    const float* __restrict__ x, const unsigned short* __restrict__ qt_bf,
    const float* __restrict__ lg, const float* __restrict__ lb,
    float* __restrict__ acc_t, float* __restrict__ accs,
    float* __restrict__ attn_out) {
  const int b  = blockIdx.x;
  const int w    = threadIdx.x >> 6;
  const int lane = threadIdx.x & 63;
  const int m    = lane & 15;
  const int quad = lane >> 4;
  // LDS plan (53760 B):
  //  [0..36864)  xs: f32 x staging [256][36]            (life: stage->LN)
  //  [0..20480)  xb: bf16 LN'd x, pixel-major [256][40] (aliases xs, after LN)
  //  [20480..29696) A_lds [4][16][72]                   (phase1 -> phase2)
  //  [36864..53760) xbT: bf16 LN'd x, f-major [32][264] (no alias)
  __shared__ __align__(16) char smem[53760];
  float* xs = (float*)smem;
  unsigned short* xb = (unsigned short*)smem;
  unsigned short (*A_lds)[16][72] = (unsigned short (*)[16][72])(smem + 20480);
  unsigned short* xbT = (unsigned short*)(smem + 36864);

  // q~ frag: A[slot=m][f=quad*8+j] (rows 8..15 are zero) — loop-invariant
  const short8 aq = *(const short8*)(qt_bf + ((size_t)b * 16 + m) * Ff + quad * 8);

  float Ss0 = 0.f, Ss1 = 0.f, Ss2 = 0.f, Ss3 = 0.f;
  floatx4 Cg0 = {0.f,0.f,0.f,0.f}, Cg1 = {0.f,0.f,0.f,0.f};

  for (int rr = 0; rr < ROUNDS; ++rr) {
    const int p0 = (blockIdx.y * ROUNDS + rr) * 256;
    if (rr) __syncthreads();   // prior round's phase-2 LDS reads complete
    // stage x coalesced -> LDS
    {
      const float4* xg4 = (const float4*)(x + ((size_t)b * Pp + p0) * Ff);
      float4 st[8];
      #pragma unroll
      for (int i = 0; i < 8; ++i) st[i] = xg4[threadIdx.x + i * 256];
      #pragma unroll
      for (int i = 0; i < 8; ++i) {
        int f4i = threadIdx.x + i * 256;
        int px = f4i >> 3, c = (f4i & 7) * 4;
        *(float4*)&xs[px * 36 + c] = st[i];
      }
    }
    __syncthreads();
    // per-thread LN (thread = pixel) into registers
    short8 pk[4];
    {
      float xv[Ff];
      #pragma unroll
      for (int j4 = 0; j4 < 8; ++j4) {
        float4 t = *(const float4*)&xs[threadIdx.x * 36 + j4 * 4];
        xv[j4*4] = t.x; xv[j4*4+1] = t.y; xv[j4*4+2] = t.z; xv[j4*4+3] = t.w;
      }
      float mu = 0.f;
      #pragma unroll
      for (int j = 0; j < Ff; ++j) mu += xv[j];
      mu *= (1.f / Ff);
      float var = 0.f;
      #pragma unroll
      for (int j = 0; j < Ff; ++j) { float d = xv[j] - mu; var = fmaf(d, d, var); }
      var *= (1.f / Ff);
      float rr2 = rsqrtf(var + EPS_LN_);
      #pragma unroll
      for (int j = 0; j < Ff; ++j) xv[j] = (xv[j] - mu) * rr2 * lg[j] + lb[j];
      #pragma unroll
      for (int j8 = 0; j8 < 4; ++j8)
        #pragma unroll
        for (int jj = 0; jj < 8; ++jj) pk[j8][jj] = (short)f2bf(xv[j8 * 8 + jj]);
    }
    __syncthreads();   // xs reads done -> safe to overwrite region as xb
    // pixel-major copy (b128-friendly for phase 1)
    #pragma unroll
    for (int j8 = 0; j8 < 4; ++j8)
      *(short8*)&xb[threadIdx.x * 40 + j8 * 8] = pk[j8];
    // f-major copy (b128-friendly for phase 2); lane-stride-1 writes = conflict-free
    #pragma unroll
    for (int j8 = 0; j8 < 4; ++j8)
      #pragma unroll
      for (int jj = 0; jj < 8; ++jj)
        xbT[(j8 * 8 + jj) * 264 + threadIdx.x] = (unsigned short)pk[j8][jj];
    __syncthreads();

    // ---- phase 1: dots (1 MFMA per 16-px tile, K=F=32) + softmax over slots
    #pragma unroll
    for (int t = 0; t < 4; ++t) {
      const int lpx = w * 64 + t * 16 + m;   // local pixel for B-frag
      const short8 bx = *(const short8*)&xb[lpx * 40 + quad * 8];
      floatx4 C = {0.f, 0.f, 0.f, 0.f};
      C = __builtin_amdgcn_mfma_f32_16x16x32_bf16(aq, bx, C, 0, 0, 0);
      // C: col=m=pixel, row=quad*4+r=slot; slot pairs in lanes {l, l^16}
      float mx = fmaxf(fmaxf(C[0], C[1]), fmaxf(C[2], C[3]));
      mx = fmaxf(mx, __shfl_xor(mx, 16, 64));
      float e0 = __expf(C[0] - mx), e1 = __expf(C[1] - mx),
            e2 = __expf(C[2] - mx), e3 = __expf(C[3] - mx);
      float s = e0 + e1 + e2 + e3;
      s += __shfl_xor(s, 16, 64);
      float inv = 1.f / s;
      float a0 = fmaf(e0, inv, EPS_ATTN_), a1 = fmaf(e1, inv, EPS_ATTN_);
      float a2 = fmaf(e2, inv, EPS_ATTN_), a3 = fmaf(e3, inv, EPS_ATTN_);
      Ss0 += a0; Ss1 += a1; Ss2 += a2; Ss3 += a3;
      const int r0 = quad * 4;   // quads 2,3 -> rows 8..15 (benign finite values)
      A_lds[w][r0 + 0][t * 16 + m] = f2bf(a0);
      A_lds[w][r0 + 1][t * 16 + m] = f2bf(a1);
      A_lds[w][r0 + 2][t * 16 + m] = f2bf(a2);
      A_lds[w][r0 + 3][t * 16 + m] = f2bf(a3);
      if (LAST && quad < 2) {
        float* ao = attn_out + ((size_t)b * Kk + r0) * Pp + p0 + w * 64 + t * 16 + m;
        ao[0] = a0; ao[Pp] = a1; ao[2 * (size_t)Pp] = a2; ao[3 * (size_t)Pp] = a3;
      }
    }
    __syncthreads();
    // ---- phase 2: acc_t[slot][f] += attn @ xn  (A from A_lds, B from f-major xbT)
    #pragma unroll
    for (int ks = 0; ks < 2; ++ks) {
      const short8 af = *(const short8*)(&A_lds[w][m][ks * 32 + quad * 8]);
      const int pxo = w * 64 + ks * 32 + quad * 8;
      const short8 xg0 = *(const short8*)&xbT[(m)      * 264 + pxo];  // f = m
      const short8 xg1 = *(const short8*)&xbT[(16 + m) * 264 + pxo];  // f = 16+m
      Cg0 = __builtin_amdgcn_mfma_f32_16x16x32_bf16(af, xg0, Cg0, 0, 0, 0);
      Cg1 = __builtin_amdgcn_mfma_f32_16x16x32_bf16(af, xg1, Cg1, 0, 0, 0);
    }
  }
  // ---- epilogue (once per block)
  Ss0 += __shfl_xor(Ss0,1,64); Ss0 += __shfl_xor(Ss0,2,64); Ss0 += __shfl_xor(Ss0,4,64); Ss0 += __shfl_xor(Ss0,8,64);
  Ss1 += __shfl_xor(Ss1,1,64); Ss1 += __shfl_xor(Ss1,2,64); Ss1 += __shfl_xor(Ss1,4,64); Ss1 += __shfl_xor(Ss1,8,64);
  Ss2 += __shfl_xor(Ss2,1,64); Ss2 += __shfl_xor(Ss2,2,64); Ss2 += __shfl_xor(Ss2,4,64); Ss2 += __shfl_xor(Ss2,8,64);
  Ss3 += __shfl_xor(Ss3,1,64); Ss3 += __shfl_xor(Ss3,2,64); Ss3 += __shfl_xor(Ss3,4,64); Ss3 += __shfl_xor(Ss3,8,64);
  if (quad < 2) {
    const int row = quad * 4;
    float* tp = acc_t + ((size_t)b * Kk + row) * Ff + m;
    #pragma unroll
    for (int r = 0; r < 4; ++r) {
      atomicAdd(tp + (size_t)r * Ff,      Cg0[r]);
      atomicAdd(tp + (size_t)r * Ff + 16, Cg1[r]);
    }
    if (m == 0) {
      atomicAdd(&accs[b * Kk + row + 0], Ss0);
      atomicAdd(&accs[b * Kk + row + 1], Ss1);
      atomicAdd(&accs[b * Kk + row + 2], Ss2);
      atomicAdd(&accs[b * Kk + row + 3], Ss3);
    }
  }
}

// ---------------- G: u = (acc_t @ Wv^T)/S -> GRUCell -> +FF -> slots' ; next q~ (or f32 out)
template <bool LAST>
__global__ __launch_bounds__(256) void gru_kernel(
    const float* __restrict__ acc_t, const float* __restrict__ accs,
    float* __restrict__ slots,
    const float* __restrict__ W_ih, const float* __restrict__ W_hh,
    const float* __restrict__ b_ih, const float* __restrict__ b_hh,
    const float* __restrict__ fg, const float* __restrict__ fb,
    const float* __restrict__ W1, const float* __restrict__ b1,
    const float* __restrict__ W2, const float* __restrict__ b2,
    const float* __restrict__ lsg, const float* __restrict__ lsb,
    const float* __restrict__ Wq, const float* __restrict__ Wv,
    const float* __restrict__ Wk,
    unsigned short* __restrict__ qt_bf,
    float* __restrict__ acc_t2, float* __restrict__ accs2,
    float* __restrict__ out_slots) {
  const int b = blockIdx.x;
  const int kh = blockIdx.y;            // slot half
  const int k = threadIdx.x >> 6;       // local slot 0..3
  const int j = threadIdx.x & 63;
  const int kg = kh * 4 + k;            // global slot
  __shared__ float WA[192 * 65];        // W_ih -> then W1 (128x65) + Wq (64x65 @8320)
  __shared__ float WB[192 * 65];        // W_hh -> then W2 (64x129)
  __shared__ float WVs[64 * 33];
  __shared__ float WKs[64 * 33];
  __shared__ float At[4][Ff];
  __shared__ float Ub[4][Dd];
  __shared__ float Hb[4][Dd];
  __shared__ float Tb[4][2 * Dd];
  __shared__ float qs[4][Dd];
  {
    const float4* gi = (const float4*)W_ih;
    const float4* gh = (const float4*)W_hh;
    #pragma unroll
    for (int i = 0; i < 12; ++i) {
      int f4i = threadIdx.x + i * 256;
      float4 vi = gi[f4i], vh = gh[f4i];
      int fi = f4i * 4, row = fi >> 6, col = fi & 63;
      float* da = &WA[row * 65 + col];
      float* db = &WB[row * 65 + col];
      da[0]=vi.x; da[1]=vi.y; da[2]=vi.z; da[3]=vi.w;
      db[0]=vh.x; db[1]=vh.y; db[2]=vh.z; db[3]=vh.w;
    }
    const float4* gv = (const float4*)Wv;
    #pragma unroll
    for (int i = 0; i < 2; ++i) {
      int f4i = threadIdx.x + i * 256;
      float4 v = gv[f4i];
      int fi = f4i * 4, row = fi >> 5, col = fi & 31;
      float* d_ = &WVs[row * 33 + col];
      d_[0]=v.x; d_[1]=v.y; d_[2]=v.z; d_[3]=v.w;
    }
    if (!LAST) {
      const float4* gk = (const float4*)Wk;
      #pragma unroll
      for (int i = 0; i < 2; ++i) {
        int f4i = threadIdx.x + i * 256;
        float4 v = gk[f4i];
        int fi = f4i * 4, row = fi >> 5, col = fi & 31;
        float* d_ = &WKs[row * 33 + col];
        d_[0]=v.x; d_[1]=v.y; d_[2]=v.z; d_[3]=v.w;
      }
    }
  }
  const size_t rk = (size_t)b * Kk + kg;
  const float S = accs[rk];
  if (j < Ff) At[k][j] = acc_t[rk * Ff + j];
  const float h = slots[rk * Dd + j];
  Hb[k][j] = h;
  __syncthreads();
  // u_d = (sum_f acc_t[f] * Wv[d][f]) / S
  float u = 0.f;
  #pragma unroll 8
  for (int f = 0; f < Ff; ++f) u = fmaf(WVs[j * 33 + f], At[k][f], u);
  u /= S;
  Ub[k][j] = u;
  __syncthreads();
  float gr = b_ih[j], gz = b_ih[64 + j], gn = b_ih[128 + j];
  float hr = b_hh[j], hz = b_hh[64 + j], hn_ = b_hh[128 + j];
  #pragma unroll 4
  for (int d = 0; d < Dd; ++d) {
    const float ud = Ub[k][d], hd = Hb[k][d];
    gr  = fmaf(WA[j * 65 + d],         ud, gr);
    gz  = fmaf(WA[(64 + j) * 65 + d],  ud, gz);
    gn  = fmaf(WA[(128 + j) * 65 + d], ud, gn);
    hr  = fmaf(WB[j * 65 + d],         hd, hr);
    hz  = fmaf(WB[(64 + j) * 65 + d],  hd, hz);
    hn_ = fmaf(WB[(128 + j) * 65 + d], hd, hn_);
  }
  const float r = 1.f / (1.f + __expf(-(gr + hr)));
  const float z = 1.f / (1.f + __expf(-(gz + hz)));
  const float n = tanhf(fmaf(r, hn_, gn));
  const float hnew = fmaf(z, h - n, n);    // (1-z)*n + z*h
  float mu  = wsum(hnew) * (1.f / 64.f);
  float dc  = hnew - mu;
  float var = wsum(dc * dc) * (1.f / 64.f);
  float fi_ = dc * rsqrtf(var + EPS_LN_) * fg[j] + fb[j];
  __syncthreads();   // all reads of WA/WB/Ub done
  Ub[k][j] = fi_;
  {
    const float4* g1 = (const float4*)W1;
    #pragma unroll
    for (int i = 0; i < 8; ++i) {
      int f4i = threadIdx.x + i * 256;
      float4 v = g1[f4i];
      int fi = f4i * 4, row = fi >> 6, col = fi & 63;
      float* d_ = &WA[row * 65 + col];
      d_[0]=v.x; d_[1]=v.y; d_[2]=v.z; d_[3]=v.w;
    }
    if (!LAST) {
      const float4* gq = (const float4*)Wq;
      #pragma unroll
      for (int i = 0; i < 4; ++i) {
        int f4i = threadIdx.x + i * 256;
        float4 v = gq[f4i];
        int fi = f4i * 4, row = fi >> 6, col = fi & 63;
        float* d_ = &WA[8320 + row * 65 + col];
        d_[0]=v.x; d_[1]=v.y; d_[2]=v.z; d_[3]=v.w;
      }
    }
    const float4* g2 = (const float4*)W2;
    #pragma unroll
    for (int i = 0; i < 8; ++i) {
      int f4i = threadIdx.x + i * 256;
      float4 v = g2[f4i];
      int fi = f4i * 4, row = fi >> 7, col = fi & 127;
      float* d_ = &WB[row * 129 + col];
      d_[0]=v.x; d_[1]=v.y; d_[2]=v.z; d_[3]=v.w;
    }
  }
  __syncthreads();
  float f1a = b1[j], f1b = b1[64 + j];
  #pragma unroll 4
  for (int d = 0; d < Dd; ++d) {
    const float t = Ub[k][d];
    f1a = fmaf(WA[j * 65 + d],        t, f1a);
    f1b = fmaf(WA[(64 + j) * 65 + d], t, f1b);
  }
  f1a = fmaxf(f1a, 0.f);
  f1b = fmaxf(f1b, 0.f);
  Tb[k][j]      = f1a;
  Tb[k][64 + j] = f1b;
  __syncthreads();
  float o = b2[j];
  #pragma unroll 4
  for (int e = 0; e < 2 * Dd; ++e) o = fmaf(WB[j * 129 + e], Tb[k][e], o);
  const float sn = hnew + o;
  if (!LAST) {
    slots[rk * Dd + j] = sn;
    float mq = wsum(sn) * (1.f / 64.f);
    float dq = sn - mq;
    float vq = wsum(dq * dq) * (1.f / 64.f);
    float xq = dq * rsqrtf(vq + EPS_LN_) * lsg[j] + lsb[j];
    Ub[k][j] = xq;      // Ub reads all done before Tb barrier
    __syncthreads();
    float q = 0.f;
    #pragma unroll 8
    for (int d = 0; d < Dd; ++d) q = fmaf(WA[8320 + j * 65 + d], Ub[k][d], q);
    qs[k][j] = q * SCALE_;
    __syncthreads();
    if (j < Ff) {
      float qt = 0.f;
      #pragma unroll 8
      for (int d = 0; d < Dd; ++d) qt = fmaf(qs[k][d], WKs[d * 33 + j], qt);
      qt_bf[((size_t)b * 16 + kg) * Ff + j]     = f2bf(qt);
      qt_bf[((size_t)b * 16 + kg + 8) * Ff + j] = 0;
      acc_t2[rk * Ff + j] = 0.f;
    }
    if (j == 0) accs2[rk] = 0.f;
  } else {
    out_slots[rk * Dd + j] = sn;
  }
}

// ---------------- final: attn *= 1/S  (f32 RMW, float4)
__global__ __launch_bounds__(256) void scale_kernel(
    const float* __restrict__ accs, float* __restrict__ attn) {
  const size_t idx = ((size_t)blockIdx.x * 256 + threadIdx.x) * 4;
  const int bk = (int)(idx >> 12);
  const float inv = 1.f / accs[bk];
  float4 v = *(float4*)(attn + idx);
  v.x *= inv; v.y *= inv; v.z *= inv; v.w *= inv;
  *(float4*)(attn + idx) = v;
}

extern "C" void kernel_launch(void* const* d_in, const int* in_sizes, int n_in,
                              void* d_out, int out_size, void* d_ws, size_t ws_size,
                              hipStream_t stream) {
  const float* x      = (const float*)d_in[0];
  const float* noise  = (const float*)d_in[1];
  const float* smu    = (const float*)d_in[2];
  const float* ssig   = (const float*)d_in[3];
  const float* Wq     = (const float*)d_in[4];
  const float* Wk     = (const float*)d_in[5];
  const float* Wv     = (const float*)d_in[6];
  const float* W_ih   = (const float*)d_in[7];
  const float* W_hh   = (const float*)d_in[8];
  const float* b_ih   = (const float*)d_in[9];
  const float* b_hh   = (const float*)d_in[10];
  const float* ln_in_g = (const float*)d_in[11];
  const float* ln_in_b = (const float*)d_in[12];
  const float* ln_s_g  = (const float*)d_in[13];
  const float* ln_s_b  = (const float*)d_in[14];
  const float* ff_g   = (const float*)d_in[15];
  const float* ff_b   = (const float*)d_in[16];
  const float* W1     = (const float*)d_in[17];
  const float* b1     = (const float*)d_in[18];
  const float* W2     = (const float*)d_in[19];
  const float* b2     = (const float*)d_in[20];

  char* ws = (char*)d_ws;
  unsigned short* qt_bf = (unsigned short*)(ws);        // 131,072 B
  float* slots  = (float*)(ws + 131072);                // 262,144 B
  float* acc_t1 = (float*)(ws + 393216);                // 131,072 B
  float* accs1  = (float*)(ws + 524288);                //   4,096 B
  float* acc_t2 = (float*)(ws + 528384);                // 131,072 B
  float* accs2  = (float*)(ws + 659456);                //   4,096 B

  float* out_slots = (float*)d_out;                     // [B,K,D] f32
  float* out_attn  = out_slots + (size_t)Bb * Kk * Dd;  // [B,K,P] f32

  init_kernel<<<dim3(Bb), dim3(512), 0, stream>>>(
      noise, smu, ssig, Wq, Wk, ln_s_g, ln_s_b, slots, qt_bf, acc_t1, accs1);
  fattn_kernel<false><<<dim3(Bb, 16 / ROUNDS), dim3(256), 0, stream>>>(
      x, qt_bf, ln_in_g, ln_in_b, acc_t1, accs1, nullptr);
  gru_kernel<false><<<dim3(Bb, 2), dim3(256), 0, stream>>>(
      acc_t1, accs1, slots, W_ih, W_hh, b_ih, b_hh, ff_g, ff_b,
      W1, b1, W2, b2, ln_s_g, ln_s_b, Wq, Wv, Wk, qt_bf, acc_t2, accs2, nullptr);
  fattn_kernel<true><<<dim3(Bb, 16 / ROUNDS), dim3(256), 0, stream>>>(
      x, qt_bf, ln_in_g, ln_in_b, acc_t2, accs2, out_attn);
  gru_kernel<true><<<dim3(Bb, 2), dim3(256), 0, stream>>>(
      acc_t2, accs2, slots, W_ih, W_hh, b_ih, b_hh, ff_g, ff_b,
      W1, b1, W2, b2, ln_s_g, ln_s_b, Wq, Wv, Wk, qt_bf, acc_t2, accs2, out_slots);
  scale_kernel<<<dim3(4096), dim3(256), 0, stream>>>(accs2, out_attn);
}